// Round 1
// baseline (1096.945 us; speedup 1.0000x reference)
//
#include <hip/hip_runtime.h>
#include <stdint.h>

#define E_DIM 1024
#define SEQ 4096
#define BATCH 8

typedef unsigned short u16;
typedef __attribute__((ext_vector_type(8))) short bf16x8;
typedef __attribute__((ext_vector_type(4))) float f32x4;

static __device__ __forceinline__ float bf2f(u16 u){
  union { unsigned u; float f; } x; x.u = ((unsigned)u) << 16; return x.f;
}
static __device__ __forceinline__ u16 f2bf(float f){
  union { float f; unsigned u; } x; x.f = f;
  unsigned r = (x.u + 0x7fffu + ((x.u >> 16) & 1u)) >> 16;
  return (u16)r;
}
static __device__ __forceinline__ void lds_fence(){
  __asm__ volatile("s_waitcnt lgkmcnt(0)" ::: "memory");
}
// async global->LDS, 16B per lane; lds ptr must be wave-uniform (HW adds lane*16)
static __device__ __forceinline__ void gload_lds16(const u16* g, u16* l){
  __builtin_amdgcn_global_load_lds(
      (const __attribute__((address_space(1))) unsigned int*)g,
      (__attribute__((address_space(3))) unsigned int*)l, 16, 0, 0);
}

// ---------------- convert fp32 -> bf16, 8 elements/thread ----------------
__global__ __launch_bounds__(256) void conv_f2b(
    const float* __restrict__ src, u16* __restrict__ dst)
{
  size_t i = ((size_t)blockIdx.x * 256 + threadIdx.x) * 8;
  float4 a = *(const float4*)(src + i);
  float4 b = *(const float4*)(src + i + 4);
  u16 tmp[8] __attribute__((aligned(16)));
  tmp[0] = f2bf(a.x); tmp[1] = f2bf(a.y); tmp[2] = f2bf(a.z); tmp[3] = f2bf(a.w);
  tmp[4] = f2bf(b.x); tmp[5] = f2bf(b.y); tmp[6] = f2bf(b.z); tmp[7] = f2bf(b.w);
  *(uint4*)(dst + i) = *(const uint4*)tmp;
}

// ---------------- prep: transpose 1024x1024 fp32 -> bf16 ----------------
__global__ __launch_bounds__(256) void prep_transpose(
    const float* __restrict__ Wkit, const float* __restrict__ Wvit,
    const float* __restrict__ Wout, u16* __restrict__ Wt_kv,
    u16* __restrict__ Wt_out)
{
  __shared__ __align__(16) float sT[64][65];
  int m = blockIdx.y;
  const float* src = (m == 0) ? Wkit : (m == 1) ? Wvit : Wout;
  u16* dst = (m == 0) ? Wt_kv : (m == 1) ? (Wt_kv + 1024 * 1024) : Wt_out;
  int tile = blockIdx.x;            // 0..255
  int r0 = (tile & 15) * 64;        // src row base
  int c0 = (tile >> 4) * 64;        // src col base
  int t = threadIdx.x;
  #pragma unroll
  for (int it = 0; it < 4; ++it){
    int idx = t + it * 256;         // 0..1023
    int r = idx >> 4, cq = idx & 15;
    float4 v = *(const float4*)(src + (size_t)(r0 + r) * 1024 + c0 + cq * 4);
    sT[r][cq * 4 + 0] = v.x; sT[r][cq * 4 + 1] = v.y;
    sT[r][cq * 4 + 2] = v.z; sT[r][cq * 4 + 3] = v.w;
  }
  __syncthreads();
  #pragma unroll
  for (int it = 0; it < 2; ++it){
    int idx = t + it * 256;         // 0..511
    int c = idx >> 3, rb = idx & 7;
    u16 tmp[8] __attribute__((aligned(16)));
    #pragma unroll
    for (int j = 0; j < 8; ++j) tmp[j] = f2bf(sT[rb * 8 + j][c]);
    *(uint4*)(dst + (size_t)(c0 + c) * 1024 + r0 + rb * 8) = *(const uint4*)tmp;
  }
}

// ---------------- prep: pack biases [b_kit | b_vit] (fp32) ----------------
__global__ __launch_bounds__(256) void prep_bias(
    const float* __restrict__ bkit, const float* __restrict__ bvit,
    float* __restrict__ bkv)
{
  int i = blockIdx.x * 256 + threadIdx.x;  // 0..2047
  bkv[i] = (i < 1024) ? bkit[i] : bvit[i - 1024];
}

// ---------------- prep: k_ti (bf16, e-order) and v_ti (bf16, [d][kh]) ----------------
__global__ __launch_bounds__(1024) void prep_ti(
    const float* __restrict__ text,
    const float* __restrict__ Wk, const float* __restrict__ bk,
    const float* __restrict__ Wv, const float* __restrict__ bv,
    u16* __restrict__ kti, u16* __restrict__ vtiT)
{
  __shared__ __align__(16) float sT[1024];
  int b = blockIdx.x;
  int m = blockIdx.y;
  int e = threadIdx.x;
  const float* W = (m == 0) ? Wk : Wv;
  const float* bias = (m == 0) ? bk : bv;
  sT[e] = text[(size_t)b * 1024 + e];
  __syncthreads();
  float acc = bias[e];
  #pragma unroll 8
  for (int k = 0; k < 1024; ++k)
    acc += sT[k] * W[(size_t)k * 1024 + e];
  u16 r = f2bf(acc);
  if (m == 0) kti[(size_t)b * 1024 + e] = r;
  else {
    int kh = e >> 6, d = e & 63;
    vtiT[(size_t)b * 1024 + d * 16 + kh] = r;
  }
}

// ---------------- main GEMM: C[M,N] = A[M,K=1024] * Bt[N,K=1024]^T + bias ----------------
// m97-style: 128x128 tile, 256 threads (4 waves, 2x2 of 64x64), BK=64,
// global_load_lds width=16 staging, row-major LDS [128][64].
// VPERM: for column tiles >= 1024 (the V half of kv), store output
// per-row transposed as [d*16 + kh] (same layout as vtiT) so the attention
// kernel reads contiguous bf16x8 B-fragments instead of stride-128B gathers.
template <typename CT, bool VPERM>
__global__ __launch_bounds__(256, 2) void gemm_bt(
    const u16* __restrict__ A, const u16* __restrict__ Bt,
    const float* __restrict__ bias, CT* __restrict__ C,
    int n_tiles, int G, int ldc)
{
  __shared__ __align__(16) u16 sA[128 * 64];
  __shared__ __align__(16) u16 sB[128 * 64];
  int bid = blockIdx.x;
  int gb = G * n_tiles;
  int g = bid / gb;
  int r = bid - g * gb;
  int mt = g * G + (r % G);
  int nt = r / G;
  int m0 = mt * 128, n0 = nt * 128;
  int tid = threadIdx.x;
  int w = tid >> 6, lane = tid & 63;
  int wm = w & 1, wn = w >> 1;
  int quad = lane >> 4, l15 = lane & 15;
  f32x4 acc[4][4];
  #pragma unroll
  for (int i = 0; i < 4; ++i)
    #pragma unroll
    for (int j = 0; j < 4; ++j)
      acc[i][j] = (f32x4){0.f, 0.f, 0.f, 0.f};
  const u16* Abase = A + (size_t)m0 * 1024;
  const u16* Bbase = Bt + (size_t)n0 * 1024;
  // staging: chunk c = i*4 + w covers LDS rows [c*8, c*8+8); lane l supplies
  // global element (row c*8 + l/8, col k0 + (l%8)*8); HW writes base + l*16B.
  int srow = lane >> 3;           // 0..7
  int scol = (lane & 7) * 8;      // 0..56
  for (int kt = 0; kt < 16; ++kt){
    int k0 = kt * 64;
    #pragma unroll
    for (int i = 0; i < 4; ++i){
      int c = i * 4 + w;
      int grow = c * 8 + srow;
      gload_lds16(Abase + (size_t)grow * 1024 + k0 + scol, sA + c * 512);
      gload_lds16(Bbase + (size_t)grow * 1024 + k0 + scol, sB + c * 512);
    }
    __syncthreads();   // compiler drains vmcnt(0) before s_barrier
    #pragma unroll
    for (int ks = 0; ks < 2; ++ks){
      bf16x8 af[4], bfr[4];
      #pragma unroll
      for (int mi = 0; mi < 4; ++mi){
        int rt = wm * 64 + mi * 16 + l15;
        af[mi] = *(const bf16x8*)(sA + rt * 64 + (ks * 4 + quad) * 8);
      }
      #pragma unroll
      for (int ni = 0; ni < 4; ++ni){
        int rt = wn * 64 + ni * 16 + l15;
        bfr[ni] = *(const bf16x8*)(sB + rt * 64 + (ks * 4 + quad) * 8);
      }
      #pragma unroll
      for (int mi = 0; mi < 4; ++mi)
        #pragma unroll
        for (int ni = 0; ni < 4; ++ni)
          acc[mi][ni] = __builtin_amdgcn_mfma_f32_16x16x32_bf16(
              af[mi], bfr[ni], acc[mi][ni], 0, 0, 0);
    }
    __syncthreads();   // all reads done before next-kt overwrite
  }
  #pragma unroll
  for (int ni = 0; ni < 4; ++ni){
    int col = n0 + wn * 64 + ni * 16 + l15;
    float bv = bias[col];
    #pragma unroll
    for (int mi = 0; mi < 4; ++mi){
      int row0 = m0 + wm * 64 + mi * 16 + quad * 4;
      #pragma unroll
      for (int rg = 0; rg < 4; ++rg){
        float v = acc[mi][ni][rg] + bv;
        size_t cidx;
        if constexpr (VPERM) {
          if (n0 >= 1024) {          // V half: per-row transposed [d*16+kh]
            int c2 = col - 1024;
            cidx = (size_t)(row0 + rg) * ldc + 1024 + (c2 & 63) * 16 + (c2 >> 6);
          } else {
            cidx = (size_t)(row0 + rg) * ldc + col;
          }
        } else {
          cidx = (size_t)(row0 + rg) * ldc + col;
        }
        if constexpr (sizeof(CT) == 2)
          C[cidx] = (CT)f2bf(v);
        else
          C[cidx] = (CT)v;
      }
    }
  }
}

// ---------------- attention: one wave per row ----------------
static __device__ __forceinline__ void softmax16(const f32x4& s, float* p){
  #pragma unroll
  for (int g = 0; g < 4; ++g){
    float v = s[g] * 0.125f;       // 1/sqrt(64)
    float m = v;
    m = fmaxf(m, __shfl_xor(m, 1, 16));
    m = fmaxf(m, __shfl_xor(m, 2, 16));
    m = fmaxf(m, __shfl_xor(m, 4, 16));
    m = fmaxf(m, __shfl_xor(m, 8, 16));
    float e = __expf(v - m);
    float t = e;
    t += __shfl_xor(t, 1, 16);
    t += __shfl_xor(t, 2, 16);
    t += __shfl_xor(t, 4, 16);
    t += __shfl_xor(t, 8, 16);
    p[g] = e / t;
  }
}

__global__ __launch_bounds__(256) void attn_kernel(
    const u16* __restrict__ img, const u16* __restrict__ text,
    const u16* __restrict__ kv, const u16* __restrict__ kti,
    const u16* __restrict__ vtiT, u16* __restrict__ attn, int b0)
{
  __shared__ __align__(16) u16 sP[4][16 * 32];
  int tid = threadIdx.x;
  int w = tid >> 6, lane = tid & 63;
  int quad = lane >> 4, l15 = lane & 15;
  u16* sPw = sP[w];
  const f32x4 fz = {0.f, 0.f, 0.f, 0.f};
  const bf16x8 bz = {0, 0, 0, 0, 0, 0, 0, 0};
  int rloc = blockIdx.x * 4 + w;       // one row per wave (4x occupancy)
  int bb = rloc >> 12;                 // 0 for 4096-row chunks
  int n = rloc & 4095;
  int b = b0 + bb;
  const u16* xrow = img + ((size_t)b * SEQ + n) * E_DIM;
  const u16* trow = text + (size_t)b * E_DIM;
  const u16* kvrow = kv + (size_t)rloc * 2048;
  u16* dst1 = attn + ((size_t)bb * 8192 + n) * E_DIM;          // img_out row
  u16* dst2 = attn + ((size_t)bb * 8192 + 4096 + n) * E_DIM;   // text_out row

  // ---------- attention 1: softmax(t_keys . k_it^T / 8) @ v_it ----------
  {
    f32x4 s = fz;
    #pragma unroll
    for (int ks = 0; ks < 2; ++ks){
      bf16x8 a  = *(const bf16x8*)(trow  + l15 * 64 + ks * 32 + quad * 8);
      bf16x8 bk = *(const bf16x8*)(kvrow + l15 * 64 + ks * 32 + quad * 8);
      s = __builtin_amdgcn_mfma_f32_16x16x32_bf16(a, bk, s, 0, 0, 0);
    }
    float p[4];
    softmax16(s, p);
    #pragma unroll
    for (int g2 = 0; g2 < 4; ++g2)
      sPw[(quad * 4 + g2) * 32 + l15] = f2bf(p[g2]);
    lds_fence();                     // writes visible before reads
    bf16x8 aP = bz;
    if (quad < 2) aP = *(const bf16x8*)(sPw + l15 * 32 + quad * 8);
    const u16* vrow = kvrow + 1024;  // VPERM layout: [d*16 + kh]
    #pragma unroll
    for (int ni = 0; ni < 4; ++ni){
      bf16x8 bV = bz;
      if (quad < 2)
        bV = *(const bf16x8*)(vrow + (ni * 16 + l15) * 16 + quad * 8);
      f32x4 o = __builtin_amdgcn_mfma_f32_16x16x32_bf16(aP, bV, fz, 0, 0, 0);
      #pragma unroll
      for (int g2 = 0; g2 < 4; ++g2)
        dst1[(quad * 4 + g2) * 64 + ni * 16 + l15] = f2bf(o[g2]);
    }
  }
  // ---------- attention 2: softmax(img . k_ti^T / 8) @ v_ti ----------
  {
    const u16* ktib = kti + (size_t)b * E_DIM;
    const u16* vtb  = vtiT + (size_t)b * E_DIM;
    f32x4 s = fz;
    #pragma unroll
    for (int ks = 0; ks < 2; ++ks){
      bf16x8 a  = *(const bf16x8*)(xrow + l15 * 64 + ks * 32 + quad * 8);
      bf16x8 bk = *(const bf16x8*)(ktib + l15 * 64 + ks * 32 + quad * 8);
      s = __builtin_amdgcn_mfma_f32_16x16x32_bf16(a, bk, s, 0, 0, 0);
    }
    float p[4];
    softmax16(s, p);
    lds_fence();                     // att1 reads done before overwrite
    #pragma unroll
    for (int g2 = 0; g2 < 4; ++g2)
      sPw[(quad * 4 + g2) * 32 + l15] = f2bf(p[g2]);
    lds_fence();
    bf16x8 aP = bz;
    if (quad < 2) aP = *(const bf16x8*)(sPw + l15 * 32 + quad * 8);
    #pragma unroll
    for (int ni = 0; ni < 4; ++ni){
      bf16x8 bV = bz;
      if (quad < 2)
        bV = *(const bf16x8*)(vtb + (ni * 16 + l15) * 16 + quad * 8);
      f32x4 o = __builtin_amdgcn_mfma_f32_16x16x32_bf16(aP, bV, fz, 0, 0, 0);
      #pragma unroll
      for (int g2 = 0; g2 < 4; ++g2)
        dst2[(quad * 4 + g2) * 64 + ni * 16 + l15] = f2bf(o[g2]);
    }
  }
}

// ---------------- host ----------------
extern "C" void kernel_launch(void* const* d_in, const int* in_sizes, int n_in,
                              void* d_out, int out_size, void* d_ws, size_t ws_size,
                              hipStream_t stream) {
  const float* img  = (const float*)d_in[0];
  const float* text = (const float*)d_in[1];
  const float* Wkit = (const float*)d_in[2];
  const float* bkit = (const float*)d_in[3];
  const float* Wvit = (const float*)d_in[4];
  const float* bvit = (const float*)d_in[5];
  const float* Wkti = (const float*)d_in[6];
  const float* bkti = (const float*)d_in[7];
  const float* Wvti = (const float*)d_in[8];
  const float* bvti = (const float*)d_in[9];
  const float* Wout = (const float*)d_in[10];
  const float* bout = (const float*)d_in[11];
  float* out = (float*)d_out;

  u16* wsp    = (u16*)d_ws;
  u16* Wt_kv  = wsp;                       // 2048*1024 u16
  u16* Wt_out = Wt_kv + 2048 * 1024;       // 1024*1024
  u16* kti    = Wt_out + 1024 * 1024;      // 8*1024
  u16* vtiT   = kti + 8 * 1024;            // 8*1024
  u16* tb16   = vtiT + 8 * 1024;           // 8*1024
  u16* imgb   = tb16 + 8 * 1024;           // 8*4096*1024
  float* bkv  = (float*)(imgb + (size_t)BATCH * SEQ * E_DIM);  // 2048 fp32
  u16* cbuf   = (u16*)(bkv + 2048);

  // prep (once per launch)
  conv_f2b<<<(BATCH * SEQ * E_DIM) / (256 * 8), 256, 0, stream>>>(img, imgb);
  conv_f2b<<<(BATCH * E_DIM) / (256 * 8), 256, 0, stream>>>(text, tb16);
  prep_transpose<<<dim3(256, 3), 256, 0, stream>>>(Wkit, Wvit, Wout, Wt_kv, Wt_out);
  prep_bias<<<8, 256, 0, stream>>>(bkit, bvit, bkv);
  prep_ti<<<dim3(8, 2), 1024, 0, stream>>>(text, Wkti, bkti, Wvti, bvti, kti, vtiT);

  // one batch per chunk
  for (int c = 0; c < 8; ++c){
    int b0 = c;
    int rows = 4096;
    u16* kvb = cbuf;                           // [rows][2048] bf16
    u16* attnb = cbuf + (size_t)rows * 2048;   // [2*rows][1024] bf16
    // GEMM1: kv_it = img_chunk @ [W_kit|W_vit] + [b_kit|b_vit]  (bf16 out, V half transposed)
    int mt1 = rows / 128, nt1 = 16;
    int G1 = (mt1 < 32) ? mt1 : 32;
    gemm_bt<u16, true><<<mt1 * nt1, 256, 0, stream>>>(
        imgb + (size_t)b0 * SEQ * E_DIM, Wt_kv, bkv, kvb, nt1, G1, 2048);
    // attention (bf16 out), one row per wave
    attn_kernel<<<rows / 4, 256, 0, stream>>>(imgb, tb16, kvb, kti, vtiT, attnb, b0);
    // GEMM2: out_chunk = attn @ W_out + b_out  (fp32 out)
    int mt2 = rows * 2 / 128, nt2 = 8;
    int G2 = (mt2 < 64) ? mt2 : 64;
    gemm_bt<float, false><<<mt2 * nt2, 256, 0, stream>>>(
        attnb, Wt_out, bout, out + (size_t)b0 * 2 * SEQ * E_DIM, nt2, G2, 1024);
  }
}

// Round 4
// 914.490 us; speedup vs baseline: 1.1995x; 1.1995x over previous
//
#include <hip/hip_runtime.h>
#include <stdint.h>

#define E_DIM 1024
#define SEQ 4096
#define BATCH 8

typedef unsigned short u16;
typedef __attribute__((ext_vector_type(8))) short bf16x8;
typedef __attribute__((ext_vector_type(4))) float f32x4;

static __device__ __forceinline__ float bf2f(u16 u){
  union { unsigned u; float f; } x; x.u = ((unsigned)u) << 16; return x.f;
}
static __device__ __forceinline__ u16 f2bf(float f){
  union { float f; unsigned u; } x; x.f = f;
  unsigned r = (x.u + 0x7fffu + ((x.u >> 16) & 1u)) >> 16;
  return (u16)r;
}
static __device__ __forceinline__ void lds_fence(){
  __asm__ volatile("s_waitcnt lgkmcnt(0)" ::: "memory");
}
// async global->LDS, 16B per lane; lds ptr must be wave-uniform (HW adds lane*16)
static __device__ __forceinline__ void gload_lds16(const u16* g, u16* l){
  __builtin_amdgcn_global_load_lds(
      (const __attribute__((address_space(1))) unsigned int*)g,
      (__attribute__((address_space(3))) unsigned int*)l, 16, 0, 0);
}

// ---------------- convert fp32 -> bf16, 8 elements/thread ----------------
__global__ __launch_bounds__(256) void conv_f2b(
    const float* __restrict__ src, u16* __restrict__ dst)
{
  size_t i = ((size_t)blockIdx.x * 256 + threadIdx.x) * 8;
  float4 a = *(const float4*)(src + i);
  float4 b = *(const float4*)(src + i + 4);
  u16 tmp[8] __attribute__((aligned(16)));
  tmp[0] = f2bf(a.x); tmp[1] = f2bf(a.y); tmp[2] = f2bf(a.z); tmp[3] = f2bf(a.w);
  tmp[4] = f2bf(b.x); tmp[5] = f2bf(b.y); tmp[6] = f2bf(b.z); tmp[7] = f2bf(b.w);
  *(uint4*)(dst + i) = *(const uint4*)tmp;
}

// ---------------- prep: transpose 1024x1024 fp32 -> bf16 ----------------
__global__ __launch_bounds__(256) void prep_transpose(
    const float* __restrict__ Wkit, const float* __restrict__ Wvit,
    const float* __restrict__ Wout, u16* __restrict__ Wt_kv,
    u16* __restrict__ Wt_out)
{
  __shared__ __align__(16) float sT[64][65];
  int m = blockIdx.y;
  const float* src = (m == 0) ? Wkit : (m == 1) ? Wvit : Wout;
  u16* dst = (m == 0) ? Wt_kv : (m == 1) ? (Wt_kv + 1024 * 1024) : Wt_out;
  int tile = blockIdx.x;            // 0..255
  int r0 = (tile & 15) * 64;        // src row base
  int c0 = (tile >> 4) * 64;        // src col base
  int t = threadIdx.x;
  #pragma unroll
  for (int it = 0; it < 4; ++it){
    int idx = t + it * 256;         // 0..1023
    int r = idx >> 4, cq = idx & 15;
    float4 v = *(const float4*)(src + (size_t)(r0 + r) * 1024 + c0 + cq * 4);
    sT[r][cq * 4 + 0] = v.x; sT[r][cq * 4 + 1] = v.y;
    sT[r][cq * 4 + 2] = v.z; sT[r][cq * 4 + 3] = v.w;
  }
  __syncthreads();
  #pragma unroll
  for (int it = 0; it < 2; ++it){
    int idx = t + it * 256;         // 0..511
    int c = idx >> 3, rb = idx & 7;
    u16 tmp[8] __attribute__((aligned(16)));
    #pragma unroll
    for (int j = 0; j < 8; ++j) tmp[j] = f2bf(sT[rb * 8 + j][c]);
    *(uint4*)(dst + (size_t)(c0 + c) * 1024 + r0 + rb * 8) = *(const uint4*)tmp;
  }
}

// ---------------- prep: pack biases [b_kit | b_vit] (fp32) ----------------
__global__ __launch_bounds__(256) void prep_bias(
    const float* __restrict__ bkit, const float* __restrict__ bvit,
    float* __restrict__ bkv)
{
  int i = blockIdx.x * 256 + threadIdx.x;  // 0..2047
  bkv[i] = (i < 1024) ? bkit[i] : bvit[i - 1024];
}

// ---------------- prep: k_ti (bf16, e-order) and v_ti (bf16, [d][kh]) ----------------
__global__ __launch_bounds__(1024) void prep_ti(
    const float* __restrict__ text,
    const float* __restrict__ Wk, const float* __restrict__ bk,
    const float* __restrict__ Wv, const float* __restrict__ bv,
    u16* __restrict__ kti, u16* __restrict__ vtiT)
{
  __shared__ __align__(16) float sT[1024];
  int b = blockIdx.x;
  int m = blockIdx.y;
  int e = threadIdx.x;
  const float* W = (m == 0) ? Wk : Wv;
  const float* bias = (m == 0) ? bk : bv;
  sT[e] = text[(size_t)b * 1024 + e];
  __syncthreads();
  float acc = bias[e];
  #pragma unroll 8
  for (int k = 0; k < 1024; ++k)
    acc += sT[k] * W[(size_t)k * 1024 + e];
  u16 r = f2bf(acc);
  if (m == 0) kti[(size_t)b * 1024 + e] = r;
  else {
    int kh = e >> 6, d = e & 63;
    vtiT[(size_t)b * 1024 + d * 16 + kh] = r;
  }
}

// ---------------- main GEMM: C[M,N] = A[M,K=1024] * Bt[N,K=1024]^T + bias ----------------
// m97-style: 128x128 tile, 256 threads (4 waves, 2x2 of 64x64), BK=64,
// global_load_lds width=16 staging, row-major LDS [128][64].
// XCD-aware bijective swizzle (grid must be a multiple of 8) + G-supertile
// so each XCD's co-resident blocks share an A-band + B-panel in its 4MB L2.
// VPERM: for column tiles >= 1024 (the V half of kv), store output per-row
// transposed as [d*16 + kh] so attention reads contiguous bf16x8 B-fragments.
template <typename CT, bool VPERM>
__global__ __launch_bounds__(256, 2) void gemm_bt(
    const u16* __restrict__ A, const u16* __restrict__ Bt,
    const float* __restrict__ bias, CT* __restrict__ C,
    int n_tiles, int G, int ldc)
{
  __shared__ __align__(16) u16 sA[128 * 64];
  __shared__ __align__(16) u16 sB[128 * 64];
  int nwg = gridDim.x;
  int cpx = nwg >> 3;                       // blocks per XCD (nwg % 8 == 0)
  int bid = (blockIdx.x & 7) * cpx + (blockIdx.x >> 3);
  int gb = G * n_tiles;
  int g = bid / gb;
  int r = bid - g * gb;
  int mt = g * G + (r % G);
  int nt = r / G;
  int m0 = mt * 128, n0 = nt * 128;
  int tid = threadIdx.x;
  int w = tid >> 6, lane = tid & 63;
  int wm = w & 1, wn = w >> 1;
  int quad = lane >> 4, l15 = lane & 15;
  f32x4 acc[4][4];
  #pragma unroll
  for (int i = 0; i < 4; ++i)
    #pragma unroll
    for (int j = 0; j < 4; ++j)
      acc[i][j] = (f32x4){0.f, 0.f, 0.f, 0.f};
  const u16* Abase = A + (size_t)m0 * 1024;
  const u16* Bbase = Bt + (size_t)n0 * 1024;
  // staging: chunk c = i*4 + w covers LDS rows [c*8, c*8+8); lane l supplies
  // global element (row c*8 + l/8, col k0 + (l%8)*8); HW writes base + l*16B.
  int srow = lane >> 3;           // 0..7
  int scol = (lane & 7) * 8;      // 0..56
  for (int kt = 0; kt < 16; ++kt){
    int k0 = kt * 64;
    #pragma unroll
    for (int i = 0; i < 4; ++i){
      int c = i * 4 + w;
      int grow = c * 8 + srow;
      gload_lds16(Abase + (size_t)grow * 1024 + k0 + scol, sA + c * 512);
      gload_lds16(Bbase + (size_t)grow * 1024 + k0 + scol, sB + c * 512);
    }
    __syncthreads();   // compiler drains vmcnt(0) before s_barrier
    #pragma unroll
    for (int ks = 0; ks < 2; ++ks){
      bf16x8 af[4], bfr[4];
      #pragma unroll
      for (int mi = 0; mi < 4; ++mi){
        int rt = wm * 64 + mi * 16 + l15;
        af[mi] = *(const bf16x8*)(sA + rt * 64 + (ks * 4 + quad) * 8);
      }
      #pragma unroll
      for (int ni = 0; ni < 4; ++ni){
        int rt = wn * 64 + ni * 16 + l15;
        bfr[ni] = *(const bf16x8*)(sB + rt * 64 + (ks * 4 + quad) * 8);
      }
      #pragma unroll
      for (int mi = 0; mi < 4; ++mi)
        #pragma unroll
        for (int ni = 0; ni < 4; ++ni)
          acc[mi][ni] = __builtin_amdgcn_mfma_f32_16x16x32_bf16(
              af[mi], bfr[ni], acc[mi][ni], 0, 0, 0);
    }
    __syncthreads();   // all reads done before next-kt overwrite
  }
  #pragma unroll
  for (int ni = 0; ni < 4; ++ni){
    int col = n0 + wn * 64 + ni * 16 + l15;
    float bv = bias[col];
    #pragma unroll
    for (int mi = 0; mi < 4; ++mi){
      int row0 = m0 + wm * 64 + mi * 16 + quad * 4;
      #pragma unroll
      for (int rg = 0; rg < 4; ++rg){
        float v = acc[mi][ni][rg] + bv;
        size_t cidx;
        if constexpr (VPERM) {
          if (n0 >= 1024) {          // V half: per-row transposed [d*16+kh]
            int c2 = col - 1024;
            cidx = (size_t)(row0 + rg) * ldc + 1024 + (c2 & 63) * 16 + (c2 >> 6);
          } else {
            cidx = (size_t)(row0 + rg) * ldc + col;
          }
        } else {
          cidx = (size_t)(row0 + rg) * ldc + col;
        }
        if constexpr (sizeof(CT) == 2)
          C[cidx] = (CT)f2bf(v);
        else
          C[cidx] = (CT)v;
      }
    }
  }
}

// ---------------- attention: one wave per row ----------------
static __device__ __forceinline__ void softmax16(const f32x4& s, float* p){
  #pragma unroll
  for (int g = 0; g < 4; ++g){
    float v = s[g] * 0.125f;       // 1/sqrt(64)
    float m = v;
    m = fmaxf(m, __shfl_xor(m, 1, 16));
    m = fmaxf(m, __shfl_xor(m, 2, 16));
    m = fmaxf(m, __shfl_xor(m, 4, 16));
    m = fmaxf(m, __shfl_xor(m, 8, 16));
    float e = __expf(v - m);
    float t = e;
    t += __shfl_xor(t, 1, 16);
    t += __shfl_xor(t, 2, 16);
    t += __shfl_xor(t, 4, 16);
    t += __shfl_xor(t, 8, 16);
    p[g] = e / t;
  }
}

__global__ __launch_bounds__(256) void attn_kernel(
    const u16* __restrict__ img, const u16* __restrict__ text,
    const u16* __restrict__ kv, const u16* __restrict__ kti,
    const u16* __restrict__ vtiT, u16* __restrict__ attn, int b0)
{
  __shared__ __align__(16) u16 sP[4][16 * 32];
  int tid = threadIdx.x;
  int w = tid >> 6, lane = tid & 63;
  int quad = lane >> 4, l15 = lane & 15;
  u16* sPw = sP[w];
  const f32x4 fz = {0.f, 0.f, 0.f, 0.f};
  const bf16x8 bz = {0, 0, 0, 0, 0, 0, 0, 0};
  int rloc = blockIdx.x * 4 + w;       // one row per wave
  int bb = rloc >> 12;                 // local batch within chunk
  int n = rloc & 4095;
  int b = b0 + bb;
  const u16* xrow = img + ((size_t)b * SEQ + n) * E_DIM;
  const u16* trow = text + (size_t)b * E_DIM;
  const u16* kvrow = kv + (size_t)rloc * 2048;
  u16* dst1 = attn + ((size_t)bb * 8192 + n) * E_DIM;          // img_out row
  u16* dst2 = attn + ((size_t)bb * 8192 + 4096 + n) * E_DIM;   // text_out row

  // ---------- attention 1: softmax(t_keys . k_it^T / 8) @ v_it ----------
  {
    f32x4 s = fz;
    #pragma unroll
    for (int ks = 0; ks < 2; ++ks){
      bf16x8 a  = *(const bf16x8*)(trow  + l15 * 64 + ks * 32 + quad * 8);
      bf16x8 bk = *(const bf16x8*)(kvrow + l15 * 64 + ks * 32 + quad * 8);
      s = __builtin_amdgcn_mfma_f32_16x16x32_bf16(a, bk, s, 0, 0, 0);
    }
    float p[4];
    softmax16(s, p);
    #pragma unroll
    for (int g2 = 0; g2 < 4; ++g2)
      sPw[(quad * 4 + g2) * 32 + l15] = f2bf(p[g2]);
    lds_fence();                     // writes visible before reads
    bf16x8 aP = bz;
    if (quad < 2) aP = *(const bf16x8*)(sPw + l15 * 32 + quad * 8);
    const u16* vrow = kvrow + 1024;  // VPERM layout: [d*16 + kh]
    #pragma unroll
    for (int ni = 0; ni < 4; ++ni){
      bf16x8 bV = bz;
      if (quad < 2)
        bV = *(const bf16x8*)(vrow + (ni * 16 + l15) * 16 + quad * 8);
      f32x4 o = __builtin_amdgcn_mfma_f32_16x16x32_bf16(aP, bV, fz, 0, 0, 0);
      #pragma unroll
      for (int g2 = 0; g2 < 4; ++g2)
        dst1[(quad * 4 + g2) * 64 + ni * 16 + l15] = f2bf(o[g2]);
    }
  }
  // ---------- attention 2: softmax(img . k_ti^T / 8) @ v_ti ----------
  {
    const u16* ktib = kti + (size_t)b * E_DIM;
    const u16* vtb  = vtiT + (size_t)b * E_DIM;
    f32x4 s = fz;
    #pragma unroll
    for (int ks = 0; ks < 2; ++ks){
      bf16x8 a  = *(const bf16x8*)(xrow + l15 * 64 + ks * 32 + quad * 8);
      bf16x8 bk = *(const bf16x8*)(ktib + l15 * 64 + ks * 32 + quad * 8);
      s = __builtin_amdgcn_mfma_f32_16x16x32_bf16(a, bk, s, 0, 0, 0);
    }
    float p[4];
    softmax16(s, p);
    lds_fence();                     // att1 reads done before overwrite
    #pragma unroll
    for (int g2 = 0; g2 < 4; ++g2)
      sPw[(quad * 4 + g2) * 32 + l15] = f2bf(p[g2]);
    lds_fence();
    bf16x8 aP = bz;
    if (quad < 2) aP = *(const bf16x8*)(sPw + l15 * 32 + quad * 8);
    #pragma unroll
    for (int ni = 0; ni < 4; ++ni){
      bf16x8 bV = bz;
      if (quad < 2)
        bV = *(const bf16x8*)(vtb + (ni * 16 + l15) * 16 + quad * 8);
      f32x4 o = __builtin_amdgcn_mfma_f32_16x16x32_bf16(aP, bV, fz, 0, 0, 0);
      #pragma unroll
      for (int g2 = 0; g2 < 4; ++g2)
        dst2[(quad * 4 + g2) * 64 + ni * 16 + l15] = f2bf(o[g2]);
    }
  }
}

// ---------------- host ----------------
extern "C" void kernel_launch(void* const* d_in, const int* in_sizes, int n_in,
                              void* d_out, int out_size, void* d_ws, size_t ws_size,
                              hipStream_t stream) {
  const float* img  = (const float*)d_in[0];
  const float* text = (const float*)d_in[1];
  const float* Wkit = (const float*)d_in[2];
  const float* bkit = (const float*)d_in[3];
  const float* Wvit = (const float*)d_in[4];
  const float* bvit = (const float*)d_in[5];
  const float* Wkti = (const float*)d_in[6];
  const float* bkti = (const float*)d_in[7];
  const float* Wvti = (const float*)d_in[8];
  const float* bvti = (const float*)d_in[9];
  const float* Wout = (const float*)d_in[10];
  const float* bout = (const float*)d_in[11];
  float* out = (float*)d_out;

  u16* wsp    = (u16*)d_ws;
  u16* Wt_kv  = wsp;                       // 2048*1024 u16
  u16* Wt_out = Wt_kv + 2048 * 1024;       // 1024*1024
  u16* kti    = Wt_out + 1024 * 1024;      // 8*1024
  u16* vtiT   = kti + 8 * 1024;            // 8*1024
  u16* tb16   = vtiT + 8 * 1024;           // 8*1024
  u16* imgb   = tb16 + 8 * 1024;           // 8*4096*1024
  float* bkv  = (float*)(imgb + (size_t)BATCH * SEQ * E_DIM);  // 2048 fp32
  u16* cbuf   = (u16*)(bkv + 2048);

  // full-batch path needs cbuf = 32768*2048 + 65536*1024 u16 = 256 MiB on top
  // of the ~71 MiB prefix; fall back to per-batch chunking if ws too small.
  size_t prefix_bytes = (size_t)((u16*)cbuf - wsp) * 2;
  size_t full_need = prefix_bytes +
      ((size_t)BATCH * SEQ * 2048 + (size_t)BATCH * 2 * SEQ * 1024) * 2;
  int CH = (ws_size >= full_need) ? BATCH : 1;   // batches per chunk
  int nc = BATCH / CH;

  // prep (once per launch)
  conv_f2b<<<(BATCH * SEQ * E_DIM) / (256 * 8), 256, 0, stream>>>(img, imgb);
  conv_f2b<<<(BATCH * E_DIM) / (256 * 8), 256, 0, stream>>>(text, tb16);
  prep_transpose<<<dim3(256, 3), 256, 0, stream>>>(Wkit, Wvit, Wout, Wt_kv, Wt_out);
  prep_bias<<<8, 256, 0, stream>>>(bkit, bvit, bkv);
  prep_ti<<<dim3(8, 2), 1024, 0, stream>>>(text, Wkti, bkti, Wvti, bvti, kti, vtiT);

  for (int c = 0; c < nc; ++c){
    int b0 = c * CH;
    int rows = CH * SEQ;
    u16* kvb = cbuf;                           // [rows][2048] bf16
    u16* attnb = cbuf + (size_t)rows * 2048;   // [2*rows][1024] bf16
    // GEMM1: kv_it = img @ [W_kit|W_vit] + [b_kit|b_vit]  (bf16 out, V half transposed)
    int mt1 = rows / 128, nt1 = 16;
    gemm_bt<u16, true><<<mt1 * nt1, 256, 0, stream>>>(
        imgb + (size_t)b0 * SEQ * E_DIM, Wt_kv, bkv, kvb, nt1, 8, 2048);
    // attention (bf16 out), one row per wave
    attn_kernel<<<rows / 4, 256, 0, stream>>>(imgb, tb16, kvb, kti, vtiT, attnb, b0);
    // GEMM2: out = attn @ W_out + b_out  (fp32 out)
    int mt2 = rows * 2 / 128, nt2 = 8;
    gemm_bt<float, false><<<mt2 * nt2, 256, 0, stream>>>(
        attnb, Wt_out, bout, out + (size_t)b0 * 2 * SEQ * E_DIM, nt2, 8, 1024);
  }
}

// Round 10
// 904.672 us; speedup vs baseline: 1.2125x; 1.0109x over previous
//
#include <hip/hip_runtime.h>
#include <stdint.h>

#define E_DIM 1024
#define SEQ 4096
#define BATCH 8

typedef unsigned short u16;
typedef __attribute__((ext_vector_type(8))) short bf16x8;
typedef __attribute__((ext_vector_type(4))) float f32x4;

static __device__ __forceinline__ float bf2f(u16 u){
  union { unsigned u; float f; } x; x.u = ((unsigned)u) << 16; return x.f;
}
static __device__ __forceinline__ u16 f2bf(float f){
  union { float f; unsigned u; } x; x.f = f;
  unsigned r = (x.u + 0x7fffu + ((x.u >> 16) & 1u)) >> 16;
  return (u16)r;
}
static __device__ __forceinline__ void lds_fence(){
  __asm__ volatile("s_waitcnt lgkmcnt(0)" ::: "memory");
}
// async global->LDS, 16B per lane; lds ptr must be wave-uniform (HW adds lane*16)
static __device__ __forceinline__ void gload_lds16(const u16* g, u16* l){
  __builtin_amdgcn_global_load_lds(
      (const __attribute__((address_space(1))) unsigned int*)g,
      (__attribute__((address_space(3))) unsigned int*)l, 16, 0, 0);
}

#define BAR()   __builtin_amdgcn_s_barrier()
#define SCHED0  __builtin_amdgcn_sched_barrier(0)
#define PRIO1   __builtin_amdgcn_s_setprio(1)
#define PRIO0   __builtin_amdgcn_s_setprio(0)
#define WAIT_LGKM0() do { asm volatile("s_waitcnt lgkmcnt(0)" ::: "memory"); SCHED0; } while (0)
#define WAIT_VM6()   do { asm volatile("s_waitcnt vmcnt(6)" ::: "memory"); SCHED0; } while (0)
#define WAIT_VM0()   do { asm volatile("s_waitcnt vmcnt(0)" ::: "memory"); SCHED0; } while (0)

// ---------------- convert fp32 -> bf16, 8 elements/thread ----------------
__global__ __launch_bounds__(256) void conv_f2b(
    const float* __restrict__ src, u16* __restrict__ dst)
{
  size_t i = ((size_t)blockIdx.x * 256 + threadIdx.x) * 8;
  float4 a = *(const float4*)(src + i);
  float4 b = *(const float4*)(src + i + 4);
  u16 tmp[8] __attribute__((aligned(16)));
  tmp[0] = f2bf(a.x); tmp[1] = f2bf(a.y); tmp[2] = f2bf(a.z); tmp[3] = f2bf(a.w);
  tmp[4] = f2bf(b.x); tmp[5] = f2bf(b.y); tmp[6] = f2bf(b.z); tmp[7] = f2bf(b.w);
  *(uint4*)(dst + i) = *(const uint4*)tmp;
}

// ---------------- prep: transpose 1024x1024 fp32 -> bf16 ----------------
__global__ __launch_bounds__(256) void prep_transpose(
    const float* __restrict__ Wkit, const float* __restrict__ Wvit,
    const float* __restrict__ Wout, u16* __restrict__ Wt_kv,
    u16* __restrict__ Wt_out)
{
  __shared__ __align__(16) float sT[64][65];
  int m = blockIdx.y;
  const float* src = (m == 0) ? Wkit : (m == 1) ? Wvit : Wout;
  u16* dst = (m == 0) ? Wt_kv : (m == 1) ? (Wt_kv + 1024 * 1024) : Wt_out;
  int tile = blockIdx.x;            // 0..255
  int r0 = (tile & 15) * 64;        // src row base
  int c0 = (tile >> 4) * 64;        // src col base
  int t = threadIdx.x;
  #pragma unroll
  for (int it = 0; it < 4; ++it){
    int idx = t + it * 256;         // 0..1023
    int r = idx >> 4, cq = idx & 15;
    float4 v = *(const float4*)(src + (size_t)(r0 + r) * 1024 + c0 + cq * 4);
    sT[r][cq * 4 + 0] = v.x; sT[r][cq * 4 + 1] = v.y;
    sT[r][cq * 4 + 2] = v.z; sT[r][cq * 4 + 3] = v.w;
  }
  __syncthreads();
  #pragma unroll
  for (int it = 0; it < 2; ++it){
    int idx = t + it * 256;         // 0..511
    int c = idx >> 3, rb = idx & 7;
    u16 tmp[8] __attribute__((aligned(16)));
    #pragma unroll
    for (int j = 0; j < 8; ++j) tmp[j] = f2bf(sT[rb * 8 + j][c]);
    *(uint4*)(dst + (size_t)(c0 + c) * 1024 + r0 + rb * 8) = *(const uint4*)tmp;
  }
}

// ---------------- prep: pack biases [b_kit | b_vit] (fp32) ----------------
__global__ __launch_bounds__(256) void prep_bias(
    const float* __restrict__ bkit, const float* __restrict__ bvit,
    float* __restrict__ bkv)
{
  int i = blockIdx.x * 256 + threadIdx.x;  // 0..2047
  bkv[i] = (i < 1024) ? bkit[i] : bvit[i - 1024];
}

// ---------------- prep: k_ti (bf16, e-order) and v_ti (bf16, [d][kh]) ----------------
__global__ __launch_bounds__(1024) void prep_ti(
    const float* __restrict__ text,
    const float* __restrict__ Wk, const float* __restrict__ bk,
    const float* __restrict__ Wv, const float* __restrict__ bv,
    u16* __restrict__ kti, u16* __restrict__ vtiT)
{
  __shared__ __align__(16) float sT[1024];
  int b = blockIdx.x;
  int m = blockIdx.y;
  int e = threadIdx.x;
  const float* W = (m == 0) ? Wk : Wv;
  const float* bias = (m == 0) ? bk : bv;
  sT[e] = text[(size_t)b * 1024 + e];
  __syncthreads();
  float acc = bias[e];
  #pragma unroll 8
  for (int k = 0; k < 1024; ++k)
    acc += sT[k] * W[(size_t)k * 1024 + e];
  u16 r = f2bf(acc);
  if (m == 0) kti[(size_t)b * 1024 + e] = r;
  else {
    int kh = e >> 6, d = e & 63;
    vtiT[(size_t)b * 1024 + d * 16 + kh] = r;
  }
}

// ================= 256x256 8-phase GEMM: C = A[M,1024] * Bt[N,1024]^T + bias ==========
// 512 threads = 8 waves (2M x 4N); per-wave 128x64 output (acc[8][4] of 16x16x32).
// LDS 128 KiB: double-buffered A(32K)+B(32K) per K-tile (BK=64), halves of 16 KiB.
// Staging: global_load_lds w=16, source pre-XOR-swizzled (chunk c of row r holds
// global chunk c^(r&7)); ds_read applies the same XOR -> 2-way bank aliasing (free).
// Pipeline (group k computes tile k from buf c=k&1; two raw s_barriers on read
// phases; counted vmcnt(6), never 0 in steady state):
//   ph1: ds-read a (wm0: all 16; wm1: 8) + b(ni0-1); stage (k+1)B1 -> buf c^1;
//        lgkm0; bar; MFMA Q(0,0); bar
//   ph2: ds-read a (wm1: 8) + b(ni2-3); stage (k+2)A0 -> buf c; lgkm0; bar;
//        MFMA Q(0,1); bar
//   ph3: stage (k+2)A1 -> buf c; MFMA Q(1,0); bar
//   ph4: stage (k+2)B0 -> buf c; vmcnt(6); bar; MFMA Q(1,1)
// Region-overwrite safety: A0 readers (wm0) front-load all a-frags at ph1; A1
// readers (wm1) finish at ph2; B0/B1 readers finish at ph2 — each stage of a
// region is issued at least one barrier after its last read. vmcnt(6) at group
// end forces everything except the 3 newest half-tiles -> tile k+1 fully
// resident before group k+1 ph1 (per-wave counters + barrier = collective).
#define MFMA_Q(MIH, NIH) do { \
  _Pragma("unroll") \
  for (int mi_ = 0; mi_ < 4; ++mi_) { \
    _Pragma("unroll") \
    for (int ni_ = 0; ni_ < 2; ++ni_) { \
      acc[(MIH)*4+mi_][(NIH)*2+ni_] = __builtin_amdgcn_mfma_f32_16x16x32_bf16( \
          a[(MIH)*4+mi_][0], b[(NIH)*2+ni_][0], acc[(MIH)*4+mi_][(NIH)*2+ni_], 0, 0, 0); \
      acc[(MIH)*4+mi_][(NIH)*2+ni_] = __builtin_amdgcn_mfma_f32_16x16x32_bf16( \
          a[(MIH)*4+mi_][1], b[(NIH)*2+ni_][1], acc[(MIH)*4+mi_][(NIH)*2+ni_], 0, 0, 0); \
    } \
  } \
} while (0)

#define STAGE_HALF(GB, LB) do { \
  gload_lds16((GB) + sP0, (LB) + (w * 2 + 0) * 512); \
  gload_lds16((GB) + sP1, (LB) + (w * 2 + 1) * 512); \
} while (0)

template <typename CT, bool VPERM>
__global__ __launch_bounds__(512, 2) void gemm256(
    const u16* __restrict__ A, const u16* __restrict__ Bt,
    const float* __restrict__ bias, CT* __restrict__ C,
    int n_tiles, int G, int ldc)
{
  __shared__ __align__(16) u16 lds[65536];   // [A|B][buf][256][64] u16, 128 KiB
  int nwg = gridDim.x;
  int cpx = nwg >> 3;                        // blocks per XCD (nwg % 8 == 0)
  int bid = (blockIdx.x & 7) * cpx + (blockIdx.x >> 3);
  int gb = G * n_tiles;
  int g = bid / gb;
  int r = bid - g * gb;
  int mt = g * G + (r % G);
  int nt = r / G;
  int m0 = mt * 256, n0 = nt * 256;
  int tid = threadIdx.x;
  int w = tid >> 6, lane = tid & 63;
  int wm = w >> 2, wn = w & 3;               // 2 x 4 waves
  int quad = lane >> 4, l15 = lane & 15;

  const u16* Ab = A + (size_t)m0 * 1024;
  const u16* Bb = Bt + (size_t)n0 * 1024;

  // per-lane staging offsets (u16 units): chunk i -> row i>>3, lds chunk i&7,
  // global chunk (i&7)^(row&7)  [inverse-swizzled source, linear LDS dest]
  int i0 = (w * 2 + 0) * 64 + lane;
  int i1 = (w * 2 + 1) * 64 + lane;
  int r0s = i0 >> 3, r1s = i1 >> 3;
  int sP0 = r0s * 1024 + (((i0 & 7) ^ (r0s & 7)) * 8);
  int sP1 = r1s * 1024 + (((i1 & 7) ^ (r1s & 7)) * 8);

  // per-lane ds_read offsets (u16 units), same XOR on the chunk index
  int swz0 = ((0 * 4 + quad) ^ (l15 & 7)) * 8;
  int swz1 = ((1 * 4 + quad) ^ (l15 & 7)) * 8;
  int ra0 = wm * 128 + l15;
  int rb0 = wn * 64 + l15;
  int aoff0 = ra0 * 64 + swz0, aoff1 = ra0 * 64 + swz1;
  int boff0 = rb0 * 64 + swz0, boff1 = rb0 * 64 + swz1;

  f32x4 acc[8][4];
  #pragma unroll
  for (int i = 0; i < 8; ++i)
    #pragma unroll
    for (int j = 0; j < 4; ++j)
      acc[i][j] = (f32x4){0.f, 0.f, 0.f, 0.f};

  // prologue: tile0 all 4 halves -> buf0; tile1 A0,A1,B0 -> buf1
  STAGE_HALF(Ab + 0,           lds + 0);
  STAGE_HALF(Ab + 131072,      lds + 8192);
  STAGE_HALF(Bb + 0,           lds + 32768);
  STAGE_HALF(Bb + 131072,      lds + 32768 + 8192);
  STAGE_HALF(Ab + 64,          lds + 16384);
  STAGE_HALF(Ab + 131072 + 64, lds + 16384 + 8192);
  STAGE_HALF(Bb + 64,          lds + 32768 + 16384);
  WAIT_VM6();
  BAR(); SCHED0;

  #pragma unroll 2
  for (int k = 0; k < 16; ++k){
    const int c = k & 1, cn = c ^ 1;
    const u16* pa = lds + c * 16384;
    const u16* pb = lds + 32768 + c * 16384;
    bf16x8 a[8][2], b[4][2];
    // ---------- phase 1 ----------
    if (wm == 0){
      #pragma unroll
      for (int mi = 0; mi < 8; ++mi){
        a[mi][0] = *(const bf16x8*)(pa + aoff0 + mi * 1024);
        a[mi][1] = *(const bf16x8*)(pa + aoff1 + mi * 1024);
      }
    } else {
      #pragma unroll
      for (int mi = 0; mi < 4; ++mi){
        a[mi][0] = *(const bf16x8*)(pa + aoff0 + mi * 1024);
        a[mi][1] = *(const bf16x8*)(pa + aoff1 + mi * 1024);
      }
    }
    #pragma unroll
    for (int ni = 0; ni < 2; ++ni){
      b[ni][0] = *(const bf16x8*)(pb + boff0 + ni * 1024);
      b[ni][1] = *(const bf16x8*)(pb + boff1 + ni * 1024);
    }
    if (k + 1 < 16)
      STAGE_HALF(Bb + 131072 + (k + 1) * 64, lds + 32768 + cn * 16384 + 8192);
    WAIT_LGKM0();
    BAR(); SCHED0;
    PRIO1; MFMA_Q(0, 0); PRIO0;
    BAR(); SCHED0;
    // ---------- phase 2 ----------
    if (wm == 1){
      #pragma unroll
      for (int mi = 4; mi < 8; ++mi){
        a[mi][0] = *(const bf16x8*)(pa + aoff0 + mi * 1024);
        a[mi][1] = *(const bf16x8*)(pa + aoff1 + mi * 1024);
      }
    }
    #pragma unroll
    for (int ni = 2; ni < 4; ++ni){
      b[ni][0] = *(const bf16x8*)(pb + boff0 + ni * 1024);
      b[ni][1] = *(const bf16x8*)(pb + boff1 + ni * 1024);
    }
    if (k + 2 < 16)
      STAGE_HALF(Ab + (k + 2) * 64, lds + c * 16384);
    WAIT_LGKM0();
    BAR(); SCHED0;
    PRIO1; MFMA_Q(0, 1); PRIO0;
    BAR(); SCHED0;
    // ---------- phase 3 ----------
    if (k + 2 < 16)
      STAGE_HALF(Ab + 131072 + (k + 2) * 64, lds + c * 16384 + 8192);
    PRIO1; MFMA_Q(1, 0); PRIO0;
    BAR(); SCHED0;
    // ---------- phase 4 ----------
    if (k + 2 < 16)
      STAGE_HALF(Bb + (k + 2) * 64, lds + 32768 + c * 16384);
    if (k < 14) { WAIT_VM6(); } else { WAIT_VM0(); }
    BAR(); SCHED0;
    PRIO1; MFMA_Q(1, 1); PRIO0;
  }

  // epilogue
  #pragma unroll
  for (int ni = 0; ni < 4; ++ni){
    int col = n0 + wn * 64 + ni * 16 + l15;
    float bv = bias[col];
    #pragma unroll
    for (int mi = 0; mi < 8; ++mi){
      int row0 = m0 + wm * 128 + mi * 16 + quad * 4;
      #pragma unroll
      for (int rg = 0; rg < 4; ++rg){
        float v = acc[mi][ni][rg] + bv;
        size_t cidx;
        if constexpr (VPERM) {
          if (n0 >= 1024) {          // V half: per-row transposed [d*16+kh]
            int c2 = col - 1024;
            cidx = (size_t)(row0 + rg) * ldc + 1024 + (c2 & 63) * 16 + (c2 >> 6);
          } else {
            cidx = (size_t)(row0 + rg) * ldc + col;
          }
        } else {
          cidx = (size_t)(row0 + rg) * ldc + col;
        }
        if constexpr (sizeof(CT) == 2)
          C[cidx] = (CT)f2bf(v);
        else
          C[cidx] = (CT)v;
      }
    }
  }
}

// ---------------- attention: one wave per row ----------------
static __device__ __forceinline__ void softmax16(const f32x4& s, float* p){
  #pragma unroll
  for (int g = 0; g < 4; ++g){
    float v = s[g] * 0.125f;       // 1/sqrt(64)
    float m = v;
    m = fmaxf(m, __shfl_xor(m, 1, 16));
    m = fmaxf(m, __shfl_xor(m, 2, 16));
    m = fmaxf(m, __shfl_xor(m, 4, 16));
    m = fmaxf(m, __shfl_xor(m, 8, 16));
    float e = __expf(v - m);
    float t = e;
    t += __shfl_xor(t, 1, 16);
    t += __shfl_xor(t, 2, 16);
    t += __shfl_xor(t, 4, 16);
    t += __shfl_xor(t, 8, 16);
    p[g] = e / t;
  }
}

__global__ __launch_bounds__(256) void attn_kernel(
    const u16* __restrict__ img, const u16* __restrict__ text,
    const u16* __restrict__ kv, const u16* __restrict__ kti,
    const u16* __restrict__ vtiT, u16* __restrict__ attn, int b0)
{
  __shared__ __align__(16) u16 sP[4][16 * 32];
  int tid = threadIdx.x;
  int w = tid >> 6, lane = tid & 63;
  int quad = lane >> 4, l15 = lane & 15;
  u16* sPw = sP[w];
  const f32x4 fz = {0.f, 0.f, 0.f, 0.f};
  const bf16x8 bz = {0, 0, 0, 0, 0, 0, 0, 0};
  int rloc = blockIdx.x * 4 + w;       // one row per wave
  int bb = rloc >> 12;                 // local batch within chunk
  int n = rloc & 4095;
  int b = b0 + bb;
  const u16* xrow = img + ((size_t)b * SEQ + n) * E_DIM;
  const u16* trow = text + (size_t)b * E_DIM;
  const u16* kvrow = kv + (size_t)rloc * 2048;
  u16* dst1 = attn + ((size_t)bb * 8192 + n) * E_DIM;          // img_out row
  u16* dst2 = attn + ((size_t)bb * 8192 + 4096 + n) * E_DIM;   // text_out row

  // ---------- attention 1: softmax(t_keys . k_it^T / 8) @ v_it ----------
  {
    f32x4 s = fz;
    #pragma unroll
    for (int ks = 0; ks < 2; ++ks){
      bf16x8 a  = *(const bf16x8*)(trow  + l15 * 64 + ks * 32 + quad * 8);
      bf16x8 bk = *(const bf16x8*)(kvrow + l15 * 64 + ks * 32 + quad * 8);
      s = __builtin_amdgcn_mfma_f32_16x16x32_bf16(a, bk, s, 0, 0, 0);
    }
    float p[4];
    softmax16(s, p);
    #pragma unroll
    for (int g2 = 0; g2 < 4; ++g2)
      sPw[(quad * 4 + g2) * 32 + l15] = f2bf(p[g2]);
    lds_fence();                     // writes visible before reads
    bf16x8 aP = bz;
    if (quad < 2) aP = *(const bf16x8*)(sPw + l15 * 32 + quad * 8);
    const u16* vrow = kvrow + 1024;  // VPERM layout: [d*16 + kh]
    #pragma unroll
    for (int ni = 0; ni < 4; ++ni){
      bf16x8 bV = bz;
      if (quad < 2)
        bV = *(const bf16x8*)(vrow + (ni * 16 + l15) * 16 + quad * 8);
      f32x4 o = __builtin_amdgcn_mfma_f32_16x16x32_bf16(aP, bV, fz, 0, 0, 0);
      #pragma unroll
      for (int g2 = 0; g2 < 4; ++g2)
        dst1[(quad * 4 + g2) * 64 + ni * 16 + l15] = f2bf(o[g2]);
    }
  }
  // ---------- attention 2: softmax(img . k_ti^T / 8) @ v_ti ----------
  {
    const u16* ktib = kti + (size_t)b * E_DIM;
    const u16* vtb  = vtiT + (size_t)b * E_DIM;
    f32x4 s = fz;
    #pragma unroll
    for (int ks = 0; ks < 2; ++ks){
      bf16x8 a  = *(const bf16x8*)(xrow + l15 * 64 + ks * 32 + quad * 8);
      bf16x8 bk = *(const bf16x8*)(ktib + l15 * 64 + ks * 32 + quad * 8);
      s = __builtin_amdgcn_mfma_f32_16x16x32_bf16(a, bk, s, 0, 0, 0);
    }
    float p[4];
    softmax16(s, p);
    lds_fence();                     // att1 reads done before overwrite
    #pragma unroll
    for (int g2 = 0; g2 < 4; ++g2)
      sPw[(quad * 4 + g2) * 32 + l15] = f2bf(p[g2]);
    lds_fence();
    bf16x8 aP = bz;
    if (quad < 2) aP = *(const bf16x8*)(sPw + l15 * 32 + quad * 8);
    #pragma unroll
    for (int ni = 0; ni < 4; ++ni){
      bf16x8 bV = bz;
      if (quad < 2)
        bV = *(const bf16x8*)(vtb + (ni * 16 + l15) * 16 + quad * 8);
      f32x4 o = __builtin_amdgcn_mfma_f32_16x16x32_bf16(aP, bV, fz, 0, 0, 0);
      #pragma unroll
      for (int g2 = 0; g2 < 4; ++g2)
        dst2[(quad * 4 + g2) * 64 + ni * 16 + l15] = f2bf(o[g2]);
    }
  }
}

// ---------------- host ----------------
extern "C" void kernel_launch(void* const* d_in, const int* in_sizes, int n_in,
                              void* d_out, int out_size, void* d_ws, size_t ws_size,
                              hipStream_t stream) {
  const float* img  = (const float*)d_in[0];
  const float* text = (const float*)d_in[1];
  const float* Wkit = (const float*)d_in[2];
  const float* bkit = (const float*)d_in[3];
  const float* Wvit = (const float*)d_in[4];
  const float* bvit = (const float*)d_in[5];
  const float* Wkti = (const float*)d_in[6];
  const float* bkti = (const float*)d_in[7];
  const float* Wvti = (const float*)d_in[8];
  const float* bvti = (const float*)d_in[9];
  const float* Wout = (const float*)d_in[10];
  const float* bout = (const float*)d_in[11];
  float* out = (float*)d_out;

  u16* wsp    = (u16*)d_ws;
  u16* Wt_kv  = wsp;                       // 2048*1024 u16
  u16* Wt_out = Wt_kv + 2048 * 1024;       // 1024*1024
  u16* kti    = Wt_out + 1024 * 1024;      // 8*1024
  u16* vtiT   = kti + 8 * 1024;            // 8*1024
  u16* tb16   = vtiT + 8 * 1024;           // 8*1024
  u16* imgb   = tb16 + 8 * 1024;           // 8*4096*1024
  float* bkv  = (float*)(imgb + (size_t)BATCH * SEQ * E_DIM);  // 2048 fp32
  u16* cbuf   = (u16*)(bkv + 2048);

  // full-batch path needs cbuf = 32768*2048 + 65536*1024 u16 = 256 MiB on top
  // of the ~71 MiB prefix; fall back to per-batch chunking if ws too small.
  size_t prefix_bytes = (size_t)((u16*)cbuf - wsp) * 2;
  size_t full_need = prefix_bytes +
      ((size_t)BATCH * SEQ * 2048 + (size_t)BATCH * 2 * SEQ * 1024) * 2;
  int CH = (ws_size >= full_need) ? BATCH : 1;   // batches per chunk
  int nc = BATCH / CH;

  // prep (once per launch)
  conv_f2b<<<(BATCH * SEQ * E_DIM) / (256 * 8), 256, 0, stream>>>(img, imgb);
  conv_f2b<<<(BATCH * E_DIM) / (256 * 8), 256, 0, stream>>>(text, tb16);
  prep_transpose<<<dim3(256, 3), 256, 0, stream>>>(Wkit, Wvit, Wout, Wt_kv, Wt_out);
  prep_bias<<<8, 256, 0, stream>>>(bkit, bvit, bkv);
  prep_ti<<<dim3(8, 2), 1024, 0, stream>>>(text, Wkti, bkti, Wvti, bvti, kti, vtiT);

  for (int c = 0; c < nc; ++c){
    int b0 = c * CH;
    int rows = CH * SEQ;
    u16* kvb = cbuf;                           // [rows][2048] bf16
    u16* attnb = cbuf + (size_t)rows * 2048;   // [2*rows][1024] bf16
    // GEMM1: kv_it = img @ [W_kit|W_vit] + [b_kit|b_vit]  (bf16 out, V half transposed)
    int mt1 = rows / 256, nt1 = 8;             // 256x256 tiles
    gemm256<u16, true><<<mt1 * nt1, 512, 0, stream>>>(
        imgb + (size_t)b0 * SEQ * E_DIM, Wt_kv, bkv, kvb, nt1, 8, 2048);
    // attention (bf16 out), one row per wave
    attn_kernel<<<rows / 4, 256, 0, stream>>>(imgb, tb16, kvb, kti, vtiT, attnb, b0);
    // GEMM2: out = attn @ W_out + b_out  (fp32 out)
    int mt2 = rows * 2 / 256, nt2 = 4;
    gemm256<float, false><<<mt2 * nt2, 512, 0, stream>>>(
        attnb, Wt_out, bout, out + (size_t)b0 * 2 * SEQ * E_DIM, nt2, 8, 1024);
  }
}

// Round 11
// 895.653 us; speedup vs baseline: 1.2247x; 1.0101x over previous
//
#include <hip/hip_runtime.h>
#include <stdint.h>

#define E_DIM 1024
#define SEQ 4096
#define BATCH 8

typedef unsigned short u16;
typedef __attribute__((ext_vector_type(8))) short bf16x8;
typedef __attribute__((ext_vector_type(4))) float f32x4;

static __device__ __forceinline__ float bf2f(u16 u){
  union { unsigned u; float f; } x; x.u = ((unsigned)u) << 16; return x.f;
}
static __device__ __forceinline__ u16 f2bf(float f){
  union { float f; unsigned u; } x; x.f = f;
  unsigned r = (x.u + 0x7fffu + ((x.u >> 16) & 1u)) >> 16;
  return (u16)r;
}
static __device__ __forceinline__ void lds_fence(){
  __asm__ volatile("s_waitcnt lgkmcnt(0)" ::: "memory");
}
// async global->LDS, 16B per lane; lds ptr must be wave-uniform (HW adds lane*16)
static __device__ __forceinline__ void gload_lds16(const u16* g, u16* l){
  __builtin_amdgcn_global_load_lds(
      (const __attribute__((address_space(1))) unsigned int*)g,
      (__attribute__((address_space(3))) unsigned int*)l, 16, 0, 0);
}

#define BAR()   __builtin_amdgcn_s_barrier()
#define SCHED0  __builtin_amdgcn_sched_barrier(0)
#define PRIO1   __builtin_amdgcn_s_setprio(1)
#define PRIO0   __builtin_amdgcn_s_setprio(0)
#define WAIT_LGKM0() do { asm volatile("s_waitcnt lgkmcnt(0)" ::: "memory"); SCHED0; } while (0)
#define WAIT_VM6()   do { asm volatile("s_waitcnt vmcnt(6)" ::: "memory"); SCHED0; } while (0)
#define WAIT_VM0()   do { asm volatile("s_waitcnt vmcnt(0)" ::: "memory"); SCHED0; } while (0)

// ---------------- convert fp32 -> bf16, 8 elements/thread ----------------
__global__ __launch_bounds__(256) void conv_f2b(
    const float* __restrict__ src, u16* __restrict__ dst)
{
  size_t i = ((size_t)blockIdx.x * 256 + threadIdx.x) * 8;
  float4 a = *(const float4*)(src + i);
  float4 b = *(const float4*)(src + i + 4);
  u16 tmp[8] __attribute__((aligned(16)));
  tmp[0] = f2bf(a.x); tmp[1] = f2bf(a.y); tmp[2] = f2bf(a.z); tmp[3] = f2bf(a.w);
  tmp[4] = f2bf(b.x); tmp[5] = f2bf(b.y); tmp[6] = f2bf(b.z); tmp[7] = f2bf(b.w);
  *(uint4*)(dst + i) = *(const uint4*)tmp;
}

// ---------------- prep: transpose 1024x1024 fp32 -> bf16 ----------------
__global__ __launch_bounds__(256) void prep_transpose(
    const float* __restrict__ Wkit, const float* __restrict__ Wvit,
    const float* __restrict__ Wout, u16* __restrict__ Wt_kv,
    u16* __restrict__ Wt_out)
{
  __shared__ __align__(16) float sT[64][65];
  int m = blockIdx.y;
  const float* src = (m == 0) ? Wkit : (m == 1) ? Wvit : Wout;
  u16* dst = (m == 0) ? Wt_kv : (m == 1) ? (Wt_kv + 1024 * 1024) : Wt_out;
  int tile = blockIdx.x;            // 0..255
  int r0 = (tile & 15) * 64;        // src row base
  int c0 = (tile >> 4) * 64;        // src col base
  int t = threadIdx.x;
  #pragma unroll
  for (int it = 0; it < 4; ++it){
    int idx = t + it * 256;         // 0..1023
    int r = idx >> 4, cq = idx & 15;
    float4 v = *(const float4*)(src + (size_t)(r0 + r) * 1024 + c0 + cq * 4);
    sT[r][cq * 4 + 0] = v.x; sT[r][cq * 4 + 1] = v.y;
    sT[r][cq * 4 + 2] = v.z; sT[r][cq * 4 + 3] = v.w;
  }
  __syncthreads();
  #pragma unroll
  for (int it = 0; it < 2; ++it){
    int idx = t + it * 256;         // 0..511
    int c = idx >> 3, rb = idx & 7;
    u16 tmp[8] __attribute__((aligned(16)));
    #pragma unroll
    for (int j = 0; j < 8; ++j) tmp[j] = f2bf(sT[rb * 8 + j][c]);
    *(uint4*)(dst + (size_t)(c0 + c) * 1024 + r0 + rb * 8) = *(const uint4*)tmp;
  }
}

// ---------------- prep: pack biases [b_kit | b_vit] (fp32) ----------------
__global__ __launch_bounds__(256) void prep_bias(
    const float* __restrict__ bkit, const float* __restrict__ bvit,
    float* __restrict__ bkv)
{
  int i = blockIdx.x * 256 + threadIdx.x;  // 0..2047
  bkv[i] = (i < 1024) ? bkit[i] : bvit[i - 1024];
}

// ---------------- prep: k_ti (bf16, e-order) and v_ti (bf16, [d][kh]) ----------------
__global__ __launch_bounds__(1024) void prep_ti(
    const float* __restrict__ text,
    const float* __restrict__ Wk, const float* __restrict__ bk,
    const float* __restrict__ Wv, const float* __restrict__ bv,
    u16* __restrict__ kti, u16* __restrict__ vtiT)
{
  __shared__ __align__(16) float sT[1024];
  int b = blockIdx.x;
  int m = blockIdx.y;
  int e = threadIdx.x;
  const float* W = (m == 0) ? Wk : Wv;
  const float* bias = (m == 0) ? bk : bv;
  sT[e] = text[(size_t)b * 1024 + e];
  __syncthreads();
  float acc = bias[e];
  #pragma unroll 8
  for (int k = 0; k < 1024; ++k)
    acc += sT[k] * W[(size_t)k * 1024 + e];
  u16 r = f2bf(acc);
  if (m == 0) kti[(size_t)b * 1024 + e] = r;
  else {
    int kh = e >> 6, d = e & 63;
    vtiT[(size_t)b * 1024 + d * 16 + kh] = r;
  }
}

// ================= 256x256 pipelined GEMM: C = A[M,1024] * Bt[N,1024]^T + bias ========
// 512 threads = 8 waves (2M x 4N); per-wave 128x64 output (acc[8][4] of 16x16x32).
// LDS 128 KiB: double-buffered A(32K)+B(32K) per K-tile (BK=64), halves of 16 KiB.
// Staging: global_load_lds w=16, source pre-XOR-swizzled; ds_read same XOR.
// READ-AHEAD schedule (v2, round-10 post-mortem): reads issue one phase before
// their consuming MFMA so the LDS drain overlaps the other quadrant's MFMA:
//   ph1: read a[0..3]+b[0..3] (16); stage B1(k+1)->buf cn; lgkm0; bar;
//        MFMA Q(0,0)=a0-3 x b0-1; bar
//   ph2: read a[4..7] (8, no wait); stage B0(k+2)->buf c; bar;
//        MFMA Q(0,1)=a0-3 x b2-3 (ph1 regs); bar      <- a[4..7] drains under MFMA
//   ph3: stage A0(k+2)->buf c; lgkm0 (already drained); bar;
//        MFMA Q(1,0)=a4-7 x b0-1; bar
//   ph4: stage A1(k+2)->buf c; vmcnt(6); bar; MFMA Q(1,1)=a4-7 x b2-3
// Region safety: B (all rows) last read ph1 -> B0 restage @ph2 is 1 barrier after;
// A rows finish ph2 -> A0 @ph3, A1 @ph4. B1(k+1)->buf cn: last read ph1 of k-1.
// vmcnt(6) FIFO at group end retires exactly tile k+1's 4 halves
// (prev group's B0,A0,A1 + this group's B1); leaves k+2's three in flight.
#define MFMA_Q(MIH, NIH) do { \
  _Pragma("unroll") \
  for (int mi_ = 0; mi_ < 4; ++mi_) { \
    _Pragma("unroll") \
    for (int ni_ = 0; ni_ < 2; ++ni_) { \
      acc[(MIH)*4+mi_][(NIH)*2+ni_] = __builtin_amdgcn_mfma_f32_16x16x32_bf16( \
          a[(MIH)*4+mi_][0], b[(NIH)*2+ni_][0], acc[(MIH)*4+mi_][(NIH)*2+ni_], 0, 0, 0); \
      acc[(MIH)*4+mi_][(NIH)*2+ni_] = __builtin_amdgcn_mfma_f32_16x16x32_bf16( \
          a[(MIH)*4+mi_][1], b[(NIH)*2+ni_][1], acc[(MIH)*4+mi_][(NIH)*2+ni_], 0, 0, 0); \
    } \
  } \
} while (0)

#define STAGE_HALF(GB, LB) do { \
  gload_lds16((GB) + sP0, (LB) + (w * 2 + 0) * 512); \
  gload_lds16((GB) + sP1, (LB) + (w * 2 + 1) * 512); \
} while (0)

template <typename CT, bool VPERM>
__global__ __launch_bounds__(512, 2) void gemm256(
    const u16* __restrict__ A, const u16* __restrict__ Bt,
    const float* __restrict__ bias, CT* __restrict__ C,
    int n_tiles, int G, int ldc)
{
  __shared__ __align__(16) u16 lds[65536];   // [A|B][buf][256][64] u16, 128 KiB
  int nwg = gridDim.x;
  int cpx = nwg >> 3;                        // blocks per XCD (nwg % 8 == 0)
  int bid = (blockIdx.x & 7) * cpx + (blockIdx.x >> 3);
  int gb = G * n_tiles;
  int g = bid / gb;
  int r = bid - g * gb;
  int mt = g * G + (r % G);
  int nt = r / G;
  int m0 = mt * 256, n0 = nt * 256;
  int tid = threadIdx.x;
  int w = tid >> 6, lane = tid & 63;
  int wm = w >> 2, wn = w & 3;               // 2 x 4 waves
  int quad = lane >> 4, l15 = lane & 15;

  const u16* Ab = A + (size_t)m0 * 1024;
  const u16* Bb = Bt + (size_t)n0 * 1024;

  // per-lane staging offsets (u16 units): chunk i -> row i>>3, lds chunk i&7,
  // global chunk (i&7)^(row&7)  [inverse-swizzled source, linear LDS dest]
  int i0 = (w * 2 + 0) * 64 + lane;
  int i1 = (w * 2 + 1) * 64 + lane;
  int r0s = i0 >> 3, r1s = i1 >> 3;
  int sP0 = r0s * 1024 + (((i0 & 7) ^ (r0s & 7)) * 8);
  int sP1 = r1s * 1024 + (((i1 & 7) ^ (r1s & 7)) * 8);

  // per-lane ds_read offsets (u16 units), same XOR on the chunk index
  int swz0 = ((0 * 4 + quad) ^ (l15 & 7)) * 8;
  int swz1 = ((1 * 4 + quad) ^ (l15 & 7)) * 8;
  int ra0 = wm * 128 + l15;
  int rb0 = wn * 64 + l15;
  int aoff0 = ra0 * 64 + swz0, aoff1 = ra0 * 64 + swz1;
  int boff0 = rb0 * 64 + swz0, boff1 = rb0 * 64 + swz1;

  f32x4 acc[8][4];
  #pragma unroll
  for (int i = 0; i < 8; ++i)
    #pragma unroll
    for (int j = 0; j < 4; ++j)
      acc[i][j] = (f32x4){0.f, 0.f, 0.f, 0.f};

  // prologue: tile0 all 4 halves -> buf0; tile1 B0,A0,A1 -> buf1
  STAGE_HALF(Ab + 0,           lds + 0);
  STAGE_HALF(Ab + 131072,      lds + 8192);
  STAGE_HALF(Bb + 0,           lds + 32768);
  STAGE_HALF(Bb + 131072,      lds + 32768 + 8192);
  STAGE_HALF(Bb + 64,          lds + 32768 + 16384);
  STAGE_HALF(Ab + 64,          lds + 16384);
  STAGE_HALF(Ab + 131072 + 64, lds + 16384 + 8192);
  WAIT_VM6();
  BAR(); SCHED0;

  #pragma unroll 2
  for (int k = 0; k < 16; ++k){
    const int c = k & 1, cn = c ^ 1;
    const u16* pa = lds + c * 16384;
    const u16* pb = lds + 32768 + c * 16384;
    bf16x8 a[8][2], b[4][2];
    // ---------- phase 1: read a[0..3] + b[0..3]; stage B1(k+1) ----------
    #pragma unroll
    for (int mi = 0; mi < 4; ++mi){
      a[mi][0] = *(const bf16x8*)(pa + aoff0 + mi * 1024);
      a[mi][1] = *(const bf16x8*)(pa + aoff1 + mi * 1024);
    }
    #pragma unroll
    for (int ni = 0; ni < 4; ++ni){
      b[ni][0] = *(const bf16x8*)(pb + boff0 + ni * 1024);
      b[ni][1] = *(const bf16x8*)(pb + boff1 + ni * 1024);
    }
    if (k + 1 < 16)
      STAGE_HALF(Bb + 131072 + (k + 1) * 64, lds + 32768 + cn * 16384 + 8192);
    WAIT_LGKM0();
    BAR(); SCHED0;
    PRIO1; MFMA_Q(0, 0); PRIO0;
    BAR(); SCHED0;
    // ---------- phase 2: read a[4..7] (no wait); stage B0(k+2); Q(0,1) ----------
    #pragma unroll
    for (int mi = 4; mi < 8; ++mi){
      a[mi][0] = *(const bf16x8*)(pa + aoff0 + mi * 1024);
      a[mi][1] = *(const bf16x8*)(pa + aoff1 + mi * 1024);
    }
    if (k + 2 < 16)
      STAGE_HALF(Bb + (k + 2) * 64, lds + 32768 + c * 16384);
    BAR(); SCHED0;
    PRIO1; MFMA_Q(0, 1); PRIO0;    // uses ph1 regs; a[4..7] drain underneath
    BAR(); SCHED0;
    // ---------- phase 3: stage A0(k+2); wait a[4..7]; Q(1,0) ----------
    if (k + 2 < 16)
      STAGE_HALF(Ab + (k + 2) * 64, lds + c * 16384);
    WAIT_LGKM0();
    BAR(); SCHED0;
    PRIO1; MFMA_Q(1, 0); PRIO0;
    BAR(); SCHED0;
    // ---------- phase 4: stage A1(k+2); vmcnt; Q(1,1) ----------
    if (k + 2 < 16)
      STAGE_HALF(Ab + 131072 + (k + 2) * 64, lds + c * 16384 + 8192);
    if (k < 14) { WAIT_VM6(); } else { WAIT_VM0(); }
    BAR(); SCHED0;
    PRIO1; MFMA_Q(1, 1); PRIO0;
  }

  // epilogue
  #pragma unroll
  for (int ni = 0; ni < 4; ++ni){
    int col = n0 + wn * 64 + ni * 16 + l15;
    float bv = bias[col];
    #pragma unroll
    for (int mi = 0; mi < 8; ++mi){
      int row0 = m0 + wm * 128 + mi * 16 + quad * 4;
      #pragma unroll
      for (int rg = 0; rg < 4; ++rg){
        float v = acc[mi][ni][rg] + bv;
        size_t cidx;
        if constexpr (VPERM) {
          if (n0 >= 1024) {          // V half: per-row transposed [d*16+kh]
            int c2 = col - 1024;
            cidx = (size_t)(row0 + rg) * ldc + 1024 + (c2 & 63) * 16 + (c2 >> 6);
          } else {
            cidx = (size_t)(row0 + rg) * ldc + col;
          }
        } else {
          cidx = (size_t)(row0 + rg) * ldc + col;
        }
        if constexpr (sizeof(CT) == 2)
          C[cidx] = (CT)f2bf(v);
        else
          C[cidx] = (CT)v;
      }
    }
  }
}

// ---------------- attention: one wave per row ----------------
static __device__ __forceinline__ void softmax16(const f32x4& s, float* p){
  #pragma unroll
  for (int g = 0; g < 4; ++g){
    float v = s[g] * 0.125f;       // 1/sqrt(64)
    float m = v;
    m = fmaxf(m, __shfl_xor(m, 1, 16));
    m = fmaxf(m, __shfl_xor(m, 2, 16));
    m = fmaxf(m, __shfl_xor(m, 4, 16));
    m = fmaxf(m, __shfl_xor(m, 8, 16));
    float e = __expf(v - m);
    float t = e;
    t += __shfl_xor(t, 1, 16);
    t += __shfl_xor(t, 2, 16);
    t += __shfl_xor(t, 4, 16);
    t += __shfl_xor(t, 8, 16);
    p[g] = e / t;
  }
}

__global__ __launch_bounds__(256) void attn_kernel(
    const u16* __restrict__ img, const u16* __restrict__ text,
    const u16* __restrict__ kv, const u16* __restrict__ kti,
    const u16* __restrict__ vtiT, u16* __restrict__ attn, int b0)
{
  __shared__ __align__(16) u16 sP[4][16 * 32];
  int tid = threadIdx.x;
  int w = tid >> 6, lane = tid & 63;
  int quad = lane >> 4, l15 = lane & 15;
  u16* sPw = sP[w];
  const f32x4 fz = {0.f, 0.f, 0.f, 0.f};
  const bf16x8 bz = {0, 0, 0, 0, 0, 0, 0, 0};
  int rloc = blockIdx.x * 4 + w;       // one row per wave
  int bb = rloc >> 12;                 // local batch within chunk
  int n = rloc & 4095;
  int b = b0 + bb;
  const u16* xrow = img + ((size_t)b * SEQ + n) * E_DIM;
  const u16* trow = text + (size_t)b * E_DIM;
  const u16* kvrow = kv + (size_t)rloc * 2048;
  u16* dst1 = attn + ((size_t)bb * 8192 + n) * E_DIM;          // img_out row
  u16* dst2 = attn + ((size_t)bb * 8192 + 4096 + n) * E_DIM;   // text_out row

  // ---------- attention 1: softmax(t_keys . k_it^T / 8) @ v_it ----------
  {
    f32x4 s = fz;
    #pragma unroll
    for (int ks = 0; ks < 2; ++ks){
      bf16x8 a  = *(const bf16x8*)(trow  + l15 * 64 + ks * 32 + quad * 8);
      bf16x8 bk = *(const bf16x8*)(kvrow + l15 * 64 + ks * 32 + quad * 8);
      s = __builtin_amdgcn_mfma_f32_16x16x32_bf16(a, bk, s, 0, 0, 0);
    }
    float p[4];
    softmax16(s, p);
    #pragma unroll
    for (int g2 = 0; g2 < 4; ++g2)
      sPw[(quad * 4 + g2) * 32 + l15] = f2bf(p[g2]);
    lds_fence();                     // writes visible before reads
    bf16x8 aP = bz;
    if (quad < 2) aP = *(const bf16x8*)(sPw + l15 * 32 + quad * 8);
    const u16* vrow = kvrow + 1024;  // VPERM layout: [d*16 + kh]
    #pragma unroll
    for (int ni = 0; ni < 4; ++ni){
      bf16x8 bV = bz;
      if (quad < 2)
        bV = *(const bf16x8*)(vrow + (ni * 16 + l15) * 16 + quad * 8);
      f32x4 o = __builtin_amdgcn_mfma_f32_16x16x32_bf16(aP, bV, fz, 0, 0, 0);
      #pragma unroll
      for (int g2 = 0; g2 < 4; ++g2)
        dst1[(quad * 4 + g2) * 64 + ni * 16 + l15] = f2bf(o[g2]);
    }
  }
  // ---------- attention 2: softmax(img . k_ti^T / 8) @ v_ti ----------
  {
    const u16* ktib = kti + (size_t)b * E_DIM;
    const u16* vtb  = vtiT + (size_t)b * E_DIM;
    f32x4 s = fz;
    #pragma unroll
    for (int ks = 0; ks < 2; ++ks){
      bf16x8 a  = *(const bf16x8*)(xrow + l15 * 64 + ks * 32 + quad * 8);
      bf16x8 bk = *(const bf16x8*)(ktib + l15 * 64 + ks * 32 + quad * 8);
      s = __builtin_amdgcn_mfma_f32_16x16x32_bf16(a, bk, s, 0, 0, 0);
    }
    float p[4];
    softmax16(s, p);
    lds_fence();                     // att1 reads done before overwrite
    #pragma unroll
    for (int g2 = 0; g2 < 4; ++g2)
      sPw[(quad * 4 + g2) * 32 + l15] = f2bf(p[g2]);
    lds_fence();
    bf16x8 aP = bz;
    if (quad < 2) aP = *(const bf16x8*)(sPw + l15 * 32 + quad * 8);
    #pragma unroll
    for (int ni = 0; ni < 4; ++ni){
      bf16x8 bV = bz;
      if (quad < 2)
        bV = *(const bf16x8*)(vtb + (ni * 16 + l15) * 16 + quad * 8);
      f32x4 o = __builtin_amdgcn_mfma_f32_16x16x32_bf16(aP, bV, fz, 0, 0, 0);
      #pragma unroll
      for (int g2 = 0; g2 < 4; ++g2)
        dst2[(quad * 4 + g2) * 64 + ni * 16 + l15] = f2bf(o[g2]);
    }
  }
}

// ---------------- host ----------------
extern "C" void kernel_launch(void* const* d_in, const int* in_sizes, int n_in,
                              void* d_out, int out_size, void* d_ws, size_t ws_size,
                              hipStream_t stream) {
  const float* img  = (const float*)d_in[0];
  const float* text = (const float*)d_in[1];
  const float* Wkit = (const float*)d_in[2];
  const float* bkit = (const float*)d_in[3];
  const float* Wvit = (const float*)d_in[4];
  const float* bvit = (const float*)d_in[5];
  const float* Wkti = (const float*)d_in[6];
  const float* bkti = (const float*)d_in[7];
  const float* Wvti = (const float*)d_in[8];
  const float* bvti = (const float*)d_in[9];
  const float* Wout = (const float*)d_in[10];
  const float* bout = (const float*)d_in[11];
  float* out = (float*)d_out;

  u16* wsp    = (u16*)d_ws;
  u16* Wt_kv  = wsp;                       // 2048*1024 u16
  u16* Wt_out = Wt_kv + 2048 * 1024;       // 1024*1024
  u16* kti    = Wt_out + 1024 * 1024;      // 8*1024
  u16* vtiT   = kti + 8 * 1024;            // 8*1024
  u16* tb16   = vtiT + 8 * 1024;           // 8*1024
  u16* imgb   = tb16 + 8 * 1024;           // 8*4096*1024
  float* bkv  = (float*)(imgb + (size_t)BATCH * SEQ * E_DIM);  // 2048 fp32
  u16* cbuf   = (u16*)(bkv + 2048);

  // full-batch path needs cbuf = 32768*2048 + 65536*1024 u16 = 256 MiB on top
  // of the ~71 MiB prefix; fall back to per-batch chunking if ws too small.
  size_t prefix_bytes = (size_t)((u16*)cbuf - wsp) * 2;
  size_t full_need = prefix_bytes +
      ((size_t)BATCH * SEQ * 2048 + (size_t)BATCH * 2 * SEQ * 1024) * 2;
  int CH = (ws_size >= full_need) ? BATCH : 1;   // batches per chunk
  int nc = BATCH / CH;

  // prep (once per launch)
  conv_f2b<<<(BATCH * SEQ * E_DIM) / (256 * 8), 256, 0, stream>>>(img, imgb);
  conv_f2b<<<(BATCH * E_DIM) / (256 * 8), 256, 0, stream>>>(text, tb16);
  prep_transpose<<<dim3(256, 3), 256, 0, stream>>>(Wkit, Wvit, Wout, Wt_kv, Wt_out);
  prep_bias<<<8, 256, 0, stream>>>(bkit, bvit, bkv);
  prep_ti<<<dim3(8, 2), 1024, 0, stream>>>(text, Wkti, bkti, Wvti, bvti, kti, vtiT);

  for (int c = 0; c < nc; ++c){
    int b0 = c * CH;
    int rows = CH * SEQ;
    u16* kvb = cbuf;                           // [rows][2048] bf16
    u16* attnb = cbuf + (size_t)rows * 2048;   // [2*rows][1024] bf16
    // GEMM1: kv_it = img @ [W_kit|W_vit] + [b_kit|b_vit]  (bf16 out, V half transposed)
    int mt1 = rows / 256, nt1 = 8;             // 256x256 tiles
    gemm256<u16, true><<<mt1 * nt1, 512, 0, stream>>>(
        imgb + (size_t)b0 * SEQ * E_DIM, Wt_kv, bkv, kvb, nt1, 8, 2048);
    // attention (bf16 out), one row per wave
    attn_kernel<<<rows / 4, 256, 0, stream>>>(imgb, tb16, kvb, kti, vtiT, attnb, b0);
    // GEMM2: out = attn @ W_out + b_out  (fp32 out)
    int mt2 = rows * 2 / 256, nt2 = 4;
    gemm256<float, false><<<mt2 * nt2, 512, 0, stream>>>(
        attnb, Wt_out, bout, out + (size_t)b0 * 2 * SEQ * E_DIM, nt2, 8, 1024);
  }
}